// Round 8
// baseline (744.713 us; speedup 1.0000x reference)
//
#include <hip/hip_runtime.h>
#include <stdint.h>

// Problem constants
#define M_TOTAL 65536       // B*S = 16*4096
#define DIM     1024        // D = K
#define NQKV    3072        // Q|K|V concatenated output cols
#define NHEAD   16
#define HDIM    64

typedef __attribute__((ext_vector_type(8))) _Float16 f16x8;
typedef __attribute__((ext_vector_type(4))) _Float16 f16x4;
typedef __attribute__((ext_vector_type(4))) float    f32x4;

// ---------------------------------------------- prep: W (K x N) -> Wt f16 (N x K), 3 mats
__global__ void cvt_w_kernel(const float* __restrict__ Wq,
                             const float* __restrict__ Wk,
                             const float* __restrict__ Wv,
                             _Float16* __restrict__ Wt) {
    __shared__ float tile[32][33];
    int which = blockIdx.z;
    const float* W = (which == 0) ? Wq : (which == 1) ? Wk : Wv;
    int d0 = blockIdx.y * 32, n0 = blockIdx.x * 32;
    int tx = threadIdx.x, ty = threadIdx.y;
    tile[ty][tx] = W[(size_t)(d0 + ty) * DIM + n0 + tx];
    __syncthreads();
    Wt[(size_t)(which * DIM + n0 + ty) * DIM + d0 + tx] = (_Float16)tile[tx][ty];
}

// ---------------------------------------------------------------- prep: bias concat
__global__ __launch_bounds__(256) void bias_kernel(const float* __restrict__ bq,
                                                   const float* __restrict__ bk,
                                                   const float* __restrict__ bv,
                                                   float* __restrict__ bias) {
    int i = blockIdx.x * 256 + threadIdx.x;
    if (i < NQKV)
        bias[i] = (i < 1024) ? bq[i] : (i < 2048) ? bk[i - 1024] : bv[i - 2048];
}

// ---------------------------------------------------------------- fused QKV GEMM
// Round-5 structure (3072 blocks, 256x256 tile, BK=64, 8 waves, 8-phase,
// counted vmcnt, XOR-swizzled LDS, XCD block swizzle, LDS-bounce epilogue)
// with the x->f16 conversion FUSED into A-staging (cvt_x kernel deleted):
//  - A is staged from x (f32) via T14 reg-staging: 8 coalesced dwordx4 loads
//    issued at PH0/PH4, converted + ds_write_b64 (swizzled, conflict-free)
//    at PH3/PH7 after the counted vmcnt, published by the same barrier.
//  - B stays on global_load_lds with pre-swizzled source.
// vmcnt ledger (per wave, steady state at PH0 entry: 4 = B(u+1) halves):
//   PH0 +8 A-loads, PH2 +2, PH3 +2 -> VMCNT(4) retires B(u+1)+A-loads;
//   symmetric at PH4..PH7. Prologue/peel re-derived below.

#define LDSA(slot)  ((slot) << 15)
#define LDSB(slot)  (65536 + ((slot) << 15))

// 16 MFMAs, operand-swapped: D = b x a => lane owns m-row = l&15, n-cols contiguous
#define MFMA_Q(MIBASE, NIBASE)                                                  \
    __builtin_amdgcn_s_setprio(1);                                              \
    _Pragma("unroll") for (int mi = 0; mi < 4; ++mi)                            \
    _Pragma("unroll") for (int ni = 0; ni < 2; ++ni)                            \
    _Pragma("unroll") for (int ks = 0; ks < 2; ++ks)                            \
        acc[(MIBASE) + mi][(NIBASE) + ni] = __builtin_amdgcn_mfma_f32_16x16x32_f16( \
            b[(NIBASE) + ni][ks], a[mi][ks], acc[(MIBASE) + mi][(NIBASE) + ni], 0, 0, 0); \
    __builtin_amdgcn_s_setprio(0);

#define LGKM0    do { asm volatile("s_waitcnt lgkmcnt(0)" ::: "memory");        \
                      __builtin_amdgcn_sched_barrier(0); } while (0)
#define VMCNT(n) do { asm volatile("s_waitcnt vmcnt(" #n ")" ::: "memory");     \
                      __builtin_amdgcn_sched_barrier(0); } while (0)

__global__ __launch_bounds__(512, 2) void qkv_gemm_kernel(const float* __restrict__ Xf,
                                                          const _Float16* __restrict__ Wth,
                                                          const float* __restrict__ bias,
                                                          _Float16* __restrict__ Ch) {
    extern __shared__ char smem[];

    // XCD-aware swizzle: 3072 blocks, 3072 % 8 == 0 -> bijective; 12 blocks
    // sharing an A-panel land on the same XCD -> A re-reads are L2 hits.
    const int bid = blockIdx.x;
    const int swz = (bid & 7) * (3072 / 8) + (bid >> 3);
    const int tm  = swz / (NQKV / 256);
    const int tn  = swz % (NQKV / 256);
    const int brow = tm * 256;
    const int bcol = tn * 256;

    const int tid = threadIdx.x;
    const int w   = tid >> 6;          // wave 0..7
    const int l   = tid & 63;
    const int wm  = w >> 2;            // 0..1 -> rows wm*128..+127
    const int wn  = w & 3;             // 0..3 -> cols wn*64..+63

    // ---- B staging source (inverse-swizzled): row (w*8 + l>>3), granule (l&7)^(l>>3)
    const int lrow8 = l >> 3;
    const int lcol8 = (l & 7) ^ lrow8;
    const _Float16* pBsrc = Wth + (size_t)(bcol + w * 8 + lrow8) * DIM + lcol8 * 8;

    auto stB = [&](int slot, int kt, int half) {   // one half-tile: 2 gload_lds
        const _Float16* s = pBsrc + ((size_t)half << 17) + ((size_t)kt << 6);
        char* d = smem + LDSB(slot) + (half << 14) + (w << 10);
        __builtin_amdgcn_global_load_lds((const __attribute__((address_space(1))) void*)s,
                                         (__attribute__((address_space(3))) void*)d, 16, 0, 0);
        __builtin_amdgcn_global_load_lds((const __attribute__((address_space(1))) void*)(s + (1 << 16)),
                                         (__attribute__((address_space(3))) void*)(d + 8192), 16, 0, 0);
    };

    // ---- A reg-staging from x (f32): 8 coalesced dwordx4 loads (1 KB/wave each)
    const int ar0 = (w << 2) + (l >> 4);           // row base; round j adds 32j
    const int ac  = (l & 15) << 2;                 // f32 col base (lanes 0-15 -> 256 B)
    const float* pAsrc = Xf + (size_t)(brow + ar0) * DIM + ac;
    float4 abuf[8];
    auto issueA = [&](int kt) {
#pragma unroll
        for (int j = 0; j < 8; ++j)
            abuf[j] = *(const float4*)(pAsrc + ((size_t)(32 * j) * DIM) + (kt << 6));
    };
    // cvt + swizzled ds_write_b64 (physical granule = logical ^ (row&7); 16 lanes
    // of a row span all 32 banks -> conflict-free).
    const int ag   = ac >> 3;                      // 16B granule 0..7
    const int ahalf = (ac >> 2) & 1;
    const int agsw = ag ^ (ar0 & 7);               // (ar0+32j)&7 == ar0&7
    auto writeA = [&](int slot) {
#pragma unroll
        for (int j = 0; j < 8; ++j) {
            const int r = ar0 + 32 * j;
            f16x4 h;
            h[0] = (_Float16)abuf[j].x; h[1] = (_Float16)abuf[j].y;
            h[2] = (_Float16)abuf[j].z; h[3] = (_Float16)abuf[j].w;
            *(f16x4*)(smem + LDSA(slot) + (r << 7) + (agsw << 4) + (ahalf << 3)) = h;
        }
    };

    // ---- swizzled LDS reads: physical 16B slot = logical slot ^ (row & 7)
    const int aRowB = ((wm << 7) + (l & 15)) << 7;            // row * 128 B
    const int bRowB = 65536 + (((wn << 6) + (l & 15)) << 7);
    const int xk0 = (((l >> 4) ^ (l & 7)) << 4);
    const int xk1 = ((((l >> 4) + 4) ^ (l & 7)) << 4);
    auto LDA = [&](int slot, int mi, int ks) -> f16x8 {
        return *(const f16x8*)(smem + (slot << 15) + aRowB + (mi << 11) + (ks ? xk1 : xk0));
    };
    auto LDB = [&](int slot, int ni, int ks) -> f16x8 {
        return *(const f16x8*)(smem + (slot << 15) + bRowB + (ni << 11) + (ks ? xk1 : xk0));
    };

    f32x4 acc[8][4] = {};
    f16x8 a[4][2], b[4][2];

    // ================= prologue =================
    issueA(0);                          // 8 outstanding
    stB(0, 0, 0); stB(0, 0, 1);         // 12
    VMCNT(4);                           // A(0) loads landed (B(0) 4 in flight)
    writeA(0);                          // f16 into slot0
    stB(1, 1, 0); stB(1, 1, 1);         // 8 (B0 4 + B1 4)
    VMCNT(4);                           // B(0) landed (B(1) 4 in flight = invariant)
    LGKM0;                              // A(0) ds_writes complete
    __builtin_amdgcn_s_barrier();
    __builtin_amdgcn_sched_barrier(0);

    // ================= main loop: iters 0..6 compute K-tiles 2i, 2i+1
#pragma unroll 1
    for (int i = 0; i < 7; ++i) {
        const int u = 2 * i;
        // ---- PH0 (K-tile u, slot0, m0-3 x n0-1) | issue A(u+1) f32 loads
#pragma unroll
        for (int mi = 0; mi < 4; ++mi) { a[mi][0] = LDA(0, mi, 0); a[mi][1] = LDA(0, mi, 1); }
#pragma unroll
        for (int ni = 0; ni < 2; ++ni) { b[ni][0] = LDB(0, ni, 0); b[ni][1] = LDB(0, ni, 1); }
        issueA(u + 1);
        __builtin_amdgcn_s_barrier();
        MFMA_Q(0, 0)
        __builtin_amdgcn_s_barrier();
        // ---- PH1 (m0-3 x n2-3)
        b[2][0] = LDB(0, 2, 0); b[2][1] = LDB(0, 2, 1);
        b[3][0] = LDB(0, 3, 0); b[3][1] = LDB(0, 3, 1);
        __builtin_amdgcn_s_barrier();
        MFMA_Q(0, 2)
        __builtin_amdgcn_s_barrier();
        // ---- PH2 (m4-7 x n0-1) | stage B(u+2) h0 -> slot0
#pragma unroll
        for (int mi = 0; mi < 4; ++mi) { a[mi][0] = LDA(0, mi + 4, 0); a[mi][1] = LDA(0, mi + 4, 1); }
        stB(0, u + 2, 0);
        __builtin_amdgcn_s_barrier();
        MFMA_Q(4, 0)
        __builtin_amdgcn_s_barrier();
        // ---- PH3 (m4-7 x n2-3) | stage B(u+2) h1; cvt+write A(u+1); publish both
        stB(0, u + 2, 1);
        VMCNT(4);                        // retires B(u+1) + A(u+1) loads
        writeA(1);
        LGKM0;                           // A(u+1) writes visible
        __builtin_amdgcn_s_barrier();
        __builtin_amdgcn_sched_barrier(0);
        MFMA_Q(4, 2)
        __builtin_amdgcn_s_barrier();
        // ---- PH4 (K-tile u+1, slot1, m0-3 x n0-1) | issue A(u+2) f32 loads
#pragma unroll
        for (int mi = 0; mi < 4; ++mi) { a[mi][0] = LDA(1, mi, 0); a[mi][1] = LDA(1, mi, 1); }
#pragma unroll
        for (int ni = 0; ni < 2; ++ni) { b[ni][0] = LDB(1, ni, 0); b[ni][1] = LDB(1, ni, 1); }
        issueA(u + 2);
        __builtin_amdgcn_s_barrier();
        MFMA_Q(0, 0)
        __builtin_amdgcn_s_barrier();
        // ---- PH5 (m0-3 x n2-3)
        b[2][0] = LDB(1, 2, 0); b[2][1] = LDB(1, 2, 1);
        b[3][0] = LDB(1, 3, 0); b[3][1] = LDB(1, 3, 1);
        __builtin_amdgcn_s_barrier();
        MFMA_Q(0, 2)
        __builtin_amdgcn_s_barrier();
        // ---- PH6 (m4-7 x n0-1) | stage B(u+3) h0 -> slot1
#pragma unroll
        for (int mi = 0; mi < 4; ++mi) { a[mi][0] = LDA(1, mi + 4, 0); a[mi][1] = LDA(1, mi + 4, 1); }
        stB(1, u + 3, 0);
        __builtin_amdgcn_s_barrier();
        MFMA_Q(4, 0)
        __builtin_amdgcn_s_barrier();
        // ---- PH7 (m4-7 x n2-3) | stage B(u+3) h1; cvt+write A(u+2); publish both
        stB(1, u + 3, 1);
        VMCNT(4);                        // retires B(u+2) + A(u+2) loads
        writeA(0);
        LGKM0;
        __builtin_amdgcn_s_barrier();
        __builtin_amdgcn_sched_barrier(0);
        MFMA_Q(4, 2)
        __builtin_amdgcn_s_barrier();
    }

    // ================= peeled last iteration (K-tiles 14, 15)
    {
        // PH0 | issue A(15)
#pragma unroll
        for (int mi = 0; mi < 4; ++mi) { a[mi][0] = LDA(0, mi, 0); a[mi][1] = LDA(0, mi, 1); }
#pragma unroll
        for (int ni = 0; ni < 2; ++ni) { b[ni][0] = LDB(0, ni, 0); b[ni][1] = LDB(0, ni, 1); }
        issueA(15);
        __builtin_amdgcn_s_barrier();
        MFMA_Q(0, 0)
        __builtin_amdgcn_s_barrier();
        // PH1
        b[2][0] = LDB(0, 2, 0); b[2][1] = LDB(0, 2, 1);
        b[3][0] = LDB(0, 3, 0); b[3][1] = LDB(0, 3, 1);
        __builtin_amdgcn_s_barrier();
        MFMA_Q(0, 2)
        __builtin_amdgcn_s_barrier();
        // PH2
#pragma unroll
        for (int mi = 0; mi < 4; ++mi) { a[mi][0] = LDA(0, mi + 4, 0); a[mi][1] = LDA(0, mi + 4, 1); }
        __builtin_amdgcn_s_barrier();
        MFMA_Q(4, 0)
        __builtin_amdgcn_s_barrier();
        // PH3 | drain all (B(15) + A(15) loads); write A(15); publish
        VMCNT(0);
        writeA(1);
        LGKM0;
        __builtin_amdgcn_s_barrier();
        __builtin_amdgcn_sched_barrier(0);
        MFMA_Q(4, 2)
        __builtin_amdgcn_s_barrier();
        // PH4-7: plain compute of K-tile 15 (slot1)
#pragma unroll
        for (int mi = 0; mi < 4; ++mi) { a[mi][0] = LDA(1, mi, 0); a[mi][1] = LDA(1, mi, 1); }
#pragma unroll
        for (int ni = 0; ni < 2; ++ni) { b[ni][0] = LDB(1, ni, 0); b[ni][1] = LDB(1, ni, 1); }
        __builtin_amdgcn_s_barrier();
        MFMA_Q(0, 0)
        __builtin_amdgcn_s_barrier();
        b[2][0] = LDB(1, 2, 0); b[2][1] = LDB(1, 2, 1);
        b[3][0] = LDB(1, 3, 0); b[3][1] = LDB(1, 3, 1);
        __builtin_amdgcn_s_barrier();
        MFMA_Q(0, 2)
        __builtin_amdgcn_s_barrier();
#pragma unroll
        for (int mi = 0; mi < 4; ++mi) { a[mi][0] = LDA(1, mi + 4, 0); a[mi][1] = LDA(1, mi + 4, 1); }
        __builtin_amdgcn_s_barrier();
        MFMA_Q(4, 0)
        MFMA_Q(4, 2)
    }

    // ================= epilogue: LDS bounce -> coalesced f16x8 stores.
    // Transposed acc: lane owns m-row = l&15, n-cols (wn*64 + ni*16 + (l>>4)*4 + j).
    __syncthreads();   // full drain; smem reused as 256x256 f16
#pragma unroll
    for (int mi = 0; mi < 8; ++mi) {
        const int m = (wm << 7) + (mi << 4) + (l & 15);
        const int msw = m & 7;
#pragma unroll
        for (int ni = 0; ni < 4; ++ni) {
            const int n0 = (wn << 6) + (ni << 4) + ((l >> 4) << 2);
            const float4 bv4 = *(const float4*)&bias[bcol + n0];
            f16x4 h;
            h[0] = (_Float16)(acc[mi][ni][0] + bv4.x);
            h[1] = (_Float16)(acc[mi][ni][1] + bv4.y);
            h[2] = (_Float16)(acc[mi][ni][2] + bv4.z);
            h[3] = (_Float16)(acc[mi][ni][3] + bv4.w);
            const int c8 = n0 >> 2;                                   // 8-byte granule
            *(f16x4*)(smem + m * 512 + (((c8 >> 1) ^ msw) << 4) + ((c8 & 1) << 3)) = h;
        }
    }
    __syncthreads();
#pragma unroll
    for (int it = 0; it < 16; ++it) {
        const int row = (tid >> 5) + (it << 4);
        const int c16 = tid & 31;
        f16x8 vv = *(const f16x8*)(smem + row * 512 + ((c16 ^ (row & 7)) << 4));
        *(f16x8*)&Ch[(size_t)(brow + row) * NQKV + bcol + (c16 << 3)] = vv;
    }
}

// ---------------------------------------------------------------- per-position attention
__global__ __launch_bounds__(256) void attn_kernel(const _Float16* __restrict__ QKVh,
                                                   float* __restrict__ out) {
    __shared__ _Float16 vlds[4][1024];
    __shared__ float attlds[4][16][16];

    const int w = threadIdx.x >> 6, l = threadIdx.x & 63;
    const size_t p = (size_t)blockIdx.x * 4 + w;
    const _Float16* base = QKVh + p * NQKV;
    const _Float16* qrow = base;
    const _Float16* krow = base + 1024;
    const _Float16* vrow = base + 2048;
    const int h = l & 15;
    const int g4 = (l >> 4) * 4;

    *(uint4*)&vlds[w][l * 16]     = *(const uint4*)&vrow[l * 16];
    *(uint4*)&vlds[w][l * 16 + 8] = *(const uint4*)&vrow[l * 16 + 8];

    const int fo = (l & 15) * HDIM + (l >> 4) * 8;
    f16x8 aK0 = *(const f16x8*)&krow[fo];
    f16x8 aK1 = *(const f16x8*)&krow[fo + 32];
    f16x8 bQ0 = *(const f16x8*)&qrow[fo];
    f16x8 bQ1 = *(const f16x8*)&qrow[fo + 32];

    f32x4 sT = {0.f, 0.f, 0.f, 0.f};
    sT = __builtin_amdgcn_mfma_f32_16x16x32_f16(aK0, bQ0, sT, 0, 0, 0);
    sT = __builtin_amdgcn_mfma_f32_16x16x32_f16(aK1, bQ1, sT, 0, 0, 0);
    // lane holds s[h = l&15][g = g4 + i] = sT[i]

    float m = fmaxf(fmaxf(sT[0], sT[1]), fmaxf(sT[2], sT[3]));
    m = fmaxf(m, __shfl_xor(m, 16));
    m = fmaxf(m, __shfl_xor(m, 32));
    float e0 = __expf(sT[0] - m), e1 = __expf(sT[1] - m);
    float e2 = __expf(sT[2] - m), e3 = __expf(sT[3] - m);
    float s = e0 + e1 + e2 + e3;
    s += __shfl_xor(s, 16);
    s += __shfl_xor(s, 32);
    const float inv = 1.0f / s;

    float4 att = make_float4(e0 * inv, e1 * inv, e2 * inv, e3 * inv);
    *(float4*)&attlds[w][h][g4] = att;
    __syncthreads();

    const int dbase = (l >> 4) * 16;
    float acc[16];
#pragma unroll
    for (int c = 0; c < 16; ++c) acc[c] = 0.f;

#pragma unroll
    for (int g = 0; g < 16; ++g) {
        const float av = attlds[w][h][g];
        f16x8 v0 = *(const f16x8*)&vlds[w][g * HDIM + dbase];
        f16x8 v1 = *(const f16x8*)&vlds[w][g * HDIM + dbase + 8];
#pragma unroll
        for (int c = 0; c < 8; ++c) {
            acc[c]     += av * (float)v0[c];
            acc[c + 8] += av * (float)v1[c];
        }
    }

    float* op = out + p * DIM + h * HDIM + dbase;
#pragma unroll
    for (int c = 0; c < 16; c += 4)
        *(float4*)(op + c) = make_float4(acc[c], acc[c + 1], acc[c + 2], acc[c + 3]);
}

// ---------------------------------------------------------------- launch
extern "C" void kernel_launch(void* const* d_in, const int* in_sizes, int n_in,
                              void* d_out, int out_size, void* d_ws, size_t ws_size,
                              hipStream_t stream) {
    const float* x  = (const float*)d_in[0];
    const float* Wq = (const float*)d_in[1];
    const float* bq = (const float*)d_in[2];
    const float* Wk = (const float*)d_in[3];
    const float* bk = (const float*)d_in[4];
    const float* Wv = (const float*)d_in[5];
    const float* bv = (const float*)d_in[6];
    float* out = (float*)d_out;

    char* ws = (char*)d_ws;
    // workspace: Wth 6291456 B | bias 12288 B | Ch 402653184 B  (~409 MiB)
    _Float16* Wth  = (_Float16*)ws;
    float*    bias = (float*)(ws + 6291456);
    _Float16* Ch   = (_Float16*)(ws + 6291456 + 12288);

    // allow 128 KiB dynamic LDS (gfx950 has 160 KiB/CU)
    (void)hipFuncSetAttribute((const void*)qkv_gemm_kernel,
                              hipFuncAttributeMaxDynamicSharedMemorySize, 131072);

    hipLaunchKernelGGL(cvt_w_kernel, dim3(32, 32, 3), dim3(32, 32), 0, stream,
                       Wq, Wk, Wv, Wth);
    hipLaunchKernelGGL(bias_kernel, dim3(12), dim3(256), 0, stream,
                       bq, bk, bv, bias);
    hipLaunchKernelGGL(qkv_gemm_kernel, dim3((M_TOTAL / 256) * (NQKV / 256)), dim3(512), 131072, stream,
                       x, Wth, bias, Ch);
    hipLaunchKernelGGL(attn_kernel, dim3(M_TOTAL / 4), dim3(256), 0, stream,
                       Ch, out);
}

// Round 9
// 645.322 us; speedup vs baseline: 1.1540x; 1.1540x over previous
//
#include <hip/hip_runtime.h>
#include <stdint.h>

// Problem constants
#define M_TOTAL 65536       // B*S = 16*4096
#define DIM     1024        // D = K
#define NQKV    3072        // Q|K|V concatenated output cols
#define NHEAD   16
#define HDIM    64

typedef __attribute__((ext_vector_type(8))) _Float16 f16x8;
typedef __attribute__((ext_vector_type(4))) _Float16 f16x4;
typedef __attribute__((ext_vector_type(4))) float    f32x4;

// ---------------------------------------------------------------- prep: x -> f16
__global__ __launch_bounds__(256) void cvt_x_kernel(const float* __restrict__ x,
                                                    _Float16* __restrict__ xh,
                                                    int n4) {
    int i = blockIdx.x * blockDim.x + threadIdx.x;
    int stride = gridDim.x * blockDim.x;
    const float4* x4 = (const float4*)x;
    f16x4* o4 = (f16x4*)xh;
    for (; i < n4; i += stride) {
        float4 v = x4[i];
        f16x4 o;
        o[0] = (_Float16)v.x; o[1] = (_Float16)v.y;
        o[2] = (_Float16)v.z; o[3] = (_Float16)v.w;
        o4[i] = o;
    }
}

// ---------------------------------------------- prep: W (K x N) -> Wt f16 (N x K), 3 mats
__global__ void cvt_w_kernel(const float* __restrict__ Wq,
                             const float* __restrict__ Wk,
                             const float* __restrict__ Wv,
                             _Float16* __restrict__ Wt) {
    __shared__ float tile[32][33];
    int which = blockIdx.z;
    const float* W = (which == 0) ? Wq : (which == 1) ? Wk : Wv;
    int d0 = blockIdx.y * 32, n0 = blockIdx.x * 32;
    int tx = threadIdx.x, ty = threadIdx.y;
    tile[ty][tx] = W[(size_t)(d0 + ty) * DIM + n0 + tx];
    __syncthreads();
    Wt[(size_t)(which * DIM + n0 + ty) * DIM + d0 + tx] = (_Float16)tile[tx][ty];
}

// ---------------------------------------------------------------- prep: bias concat
__global__ __launch_bounds__(256) void bias_kernel(const float* __restrict__ bq,
                                                   const float* __restrict__ bk,
                                                   const float* __restrict__ bv,
                                                   float* __restrict__ bias) {
    int i = blockIdx.x * 256 + threadIdx.x;
    if (i < NQKV)
        bias[i] = (i < 1024) ? bq[i] : (i < 2048) ? bk[i - 1024] : bv[i - 2048];
}

// ---------------------------------------------------------------- fused QKV GEMM
// Read-ahead pipeline: per K-tile u (slot s), 4 phases; every MFMA quadrant
// consumes ds_reads issued >=1 phase earlier, so LDS service hides under the
// matrix pipe. Quadrant order Q0(aA.bA) Q1(aA.bB) Q3(aB.bA) Q2(aB.bB) nests
// operand lifetimes so next-tile reads (PH4) overwrite only dead regs ->
// single-banked, 96 operand VGPRs (no spill). 4 barriers/tile keep the R5
// convoy. Counted vmcnt(8): stage(u+1) issued at tile-u-1 PH2, retired at
// tile-u PH3 (~4 phases of HBM cover). Staging, swizzles, XCD mapping, and
// the LDS-bounce epilogue are identical to Round 5.

#define LDSA(slot)  ((slot) << 15)
#define LDSB(slot)  (65536 + ((slot) << 15))

// 16 MFMAs, operand-swapped: D = b x a => lane owns m-row = l&15, n-cols contiguous
#define MFMAQ(AF, BF, MB, NB)                                                   \
    __builtin_amdgcn_s_setprio(1);                                              \
    _Pragma("unroll") for (int mi = 0; mi < 4; ++mi)                            \
    _Pragma("unroll") for (int ni = 0; ni < 2; ++ni)                            \
    _Pragma("unroll") for (int ks = 0; ks < 2; ++ks)                            \
        acc[(MB) + mi][(NB) + ni] = __builtin_amdgcn_mfma_f32_16x16x32_f16(     \
            BF[ni][ks], AF[mi][ks], acc[(MB) + mi][(NB) + ni], 0, 0, 0);        \
    __builtin_amdgcn_s_setprio(0);

#define SB0      __builtin_amdgcn_sched_barrier(0)
#define BARRIER  __builtin_amdgcn_s_barrier()
#define LGKM0    do { asm volatile("s_waitcnt lgkmcnt(0)" ::: "memory"); SB0; } while (0)
#define VMW(n)   do { asm volatile("s_waitcnt vmcnt(" #n ")" ::: "memory"); SB0; } while (0)

// one K-tile: PH1{read bB,aB | Q0} PH2{Q1 | lgkm0 | bar | stage} PH3{Q3 | vmcnt | bar}
// PH4{read next aA,bA | Q2}
#define TILE_FULL(S, KT, VMN)                                                   \
    READ_BB(S); READ_AB(S); SB0;                                                \
    MFMAQ(aA, bA, 0, 0)                                                         \
    BARRIER;                                                                    \
    MFMAQ(aA, bB, 0, 2)                                                         \
    LGKM0;                                                                      \
    BARRIER;                                                                    \
    stageA((S), (KT)); stageB((S), (KT));                                       \
    MFMAQ(aB, bA, 4, 0)                                                         \
    VMW(VMN);                                                                   \
    BARRIER;                                                                    \
    READ_AA(1 - (S)); READ_BA(1 - (S)); SB0;                                    \
    MFMAQ(aB, bB, 4, 2)                                                         \
    BARRIER;

#define TILE_NOSTAGE(S, VMN)                                                    \
    READ_BB(S); READ_AB(S); SB0;                                                \
    MFMAQ(aA, bA, 0, 0)                                                         \
    BARRIER;                                                                    \
    MFMAQ(aA, bB, 0, 2)                                                         \
    LGKM0;                                                                      \
    BARRIER;                                                                    \
    MFMAQ(aB, bA, 4, 0)                                                         \
    VMW(VMN);                                                                   \
    BARRIER;                                                                    \
    READ_AA(1 - (S)); READ_BA(1 - (S)); SB0;                                    \
    MFMAQ(aB, bB, 4, 2)                                                         \
    BARRIER;

__global__ __launch_bounds__(512, 2) void qkv_gemm_kernel(const _Float16* __restrict__ Xh,
                                                          const _Float16* __restrict__ Wth,
                                                          const float* __restrict__ bias,
                                                          _Float16* __restrict__ Ch) {
    extern __shared__ char smem[];

    // XCD-aware swizzle: 3072 blocks, 3072 % 8 == 0 -> bijective; 12 blocks
    // sharing an A-panel land on the same XCD -> A re-reads are L2 hits.
    const int bid = blockIdx.x;
    const int swz = (bid & 7) * (3072 / 8) + (bid >> 3);
    const int tm  = swz / (NQKV / 256);
    const int tn  = swz % (NQKV / 256);
    const int brow = tm * 256;
    const int bcol = tn * 256;

    const int tid = threadIdx.x;
    const int w   = tid >> 6;          // wave 0..7
    const int l   = tid & 63;
    const int wm  = w >> 2;            // 0..1 -> rows wm*128..+127
    const int wn  = w & 3;             // 0..3 -> cols wn*64..+63

    // ---- staging source (inverse-swizzled): thread covers row (w*8 + l>>3), slot (l&7)^(l>>3)
    const int lrow8 = l >> 3;
    const int lcol8 = (l & 7) ^ lrow8;
    const _Float16* pAsrc = Xh  + (size_t)(brow + w * 8 + lrow8) * DIM + lcol8 * 8;
    const _Float16* pBsrc = Wth + (size_t)(bcol + w * 8 + lrow8) * DIM + lcol8 * 8;

    // full K-tile stage: A (256x64 = 32 KB) or B = 4 gloads/wave of 1 KB
    auto stageA = [&](int slot, int kt) {
#pragma unroll
        for (int ln = 0; ln < 4; ++ln) {
            const _Float16* s = pAsrc + (size_t)(ln * 64) * DIM + ((size_t)kt << 6);
            char* d = smem + LDSA(slot) + ln * 8192 + (w << 10);
            __builtin_amdgcn_global_load_lds((const __attribute__((address_space(1))) void*)s,
                                             (__attribute__((address_space(3))) void*)d, 16, 0, 0);
        }
    };
    auto stageB = [&](int slot, int kt) {
#pragma unroll
        for (int ln = 0; ln < 4; ++ln) {
            const _Float16* s = pBsrc + (size_t)(ln * 64) * DIM + ((size_t)kt << 6);
            char* d = smem + LDSB(slot) + ln * 8192 + (w << 10);
            __builtin_amdgcn_global_load_lds((const __attribute__((address_space(1))) void*)s,
                                             (__attribute__((address_space(3))) void*)d, 16, 0, 0);
        }
    };

    // ---- swizzled LDS reads: physical 16B slot = logical slot ^ (row & 7)
    const int aRowB = ((wm << 7) + (l & 15)) << 7;            // row * 128 B
    const int bRowB = 65536 + (((wn << 6) + (l & 15)) << 7);
    const int xk0 = (((l >> 4) ^ (l & 7)) << 4);
    const int xk1 = ((((l >> 4) + 4) ^ (l & 7)) << 4);
    auto LDA = [&](int slot, int mi, int ks) -> f16x8 {
        return *(const f16x8*)(smem + (slot << 15) + aRowB + (mi << 11) + (ks ? xk1 : xk0));
    };
    auto LDB = [&](int slot, int ni, int ks) -> f16x8 {
        return *(const f16x8*)(smem + (slot << 15) + bRowB + (ni << 11) + (ks ? xk1 : xk0));
    };

    f32x4 acc[8][4] = {};
    f16x8 aA[4][2], aB[4][2], bA[2][2], bB[2][2];   // 96 operand VGPRs, single-banked

    auto READ_AA = [&](int slot) {   // 8 ds_reads: m0-3
#pragma unroll
        for (int mi = 0; mi < 4; ++mi) { aA[mi][0] = LDA(slot, mi, 0); aA[mi][1] = LDA(slot, mi, 1); }
    };
    auto READ_AB = [&](int slot) {   // 8 ds_reads: m4-7
#pragma unroll
        for (int mi = 0; mi < 4; ++mi) { aB[mi][0] = LDA(slot, mi + 4, 0); aB[mi][1] = LDA(slot, mi + 4, 1); }
    };
    auto READ_BA = [&](int slot) {   // 4 ds_reads: n0-1
#pragma unroll
        for (int ni = 0; ni < 2; ++ni) { bA[ni][0] = LDB(slot, ni, 0); bA[ni][1] = LDB(slot, ni, 1); }
    };
    auto READ_BB = [&](int slot) {   // 4 ds_reads: n2-3
#pragma unroll
        for (int ni = 0; ni < 2; ++ni) { bB[ni][0] = LDB(slot, ni + 2, 0); bB[ni][1] = LDB(slot, ni + 2, 1); }
    };

    // ================= prologue: stage T0->slot0, T1->slot1; publish T0; read Q0 set
    stageA(0, 0); stageB(0, 0);        // 8 outstanding
    stageA(1, 1); stageB(1, 1);        // 16
    VMW(8);                            // T0 landed (T1's 8 in flight)
    BARRIER;
    SB0;
    READ_AA(0); READ_BA(0);            // tile0 Q0 operands

    // ================= main loop: 7 iterations, tiles 0..13 (stages 2..15)
#pragma unroll 1
    for (int i = 0; i < 7; ++i) {
        const int u = 2 * i;
        TILE_FULL(0, u + 2, 8)
        TILE_FULL(1, u + 3, 8)
    }

    // ================= peeled tile 14 (slot 0): no stage; drain stage(15)
    TILE_NOSTAGE(0, 0)

    // ================= peeled tile 15 (slot 1): final
    READ_BB(1); READ_AB(1); SB0;
    MFMAQ(aA, bA, 0, 0)
    MFMAQ(aA, bB, 0, 2)
    MFMAQ(aB, bA, 4, 0)
    MFMAQ(aB, bB, 4, 2)

    // ================= epilogue: LDS bounce -> coalesced f16x8 stores.
    // Transposed acc: lane owns m-row = l&15, n-cols (wn*64 + ni*16 + (l>>4)*4 + j).
    __syncthreads();   // full drain; smem reused as 256x256 f16
#pragma unroll
    for (int mi = 0; mi < 8; ++mi) {
        const int m = (wm << 7) + (mi << 4) + (l & 15);
        const int msw = m & 7;
#pragma unroll
        for (int ni = 0; ni < 4; ++ni) {
            const int n0 = (wn << 6) + (ni << 4) + ((l >> 4) << 2);
            const float4 bv4 = *(const float4*)&bias[bcol + n0];
            f16x4 h;
            h[0] = (_Float16)(acc[mi][ni][0] + bv4.x);
            h[1] = (_Float16)(acc[mi][ni][1] + bv4.y);
            h[2] = (_Float16)(acc[mi][ni][2] + bv4.z);
            h[3] = (_Float16)(acc[mi][ni][3] + bv4.w);
            const int c8 = n0 >> 2;                                   // 8-byte granule
            *(f16x4*)(smem + m * 512 + (((c8 >> 1) ^ msw) << 4) + ((c8 & 1) << 3)) = h;
        }
    }
    __syncthreads();
#pragma unroll
    for (int it = 0; it < 16; ++it) {
        const int row = (tid >> 5) + (it << 4);
        const int c16 = tid & 31;
        f16x8 vv = *(const f16x8*)(smem + row * 512 + ((c16 ^ (row & 7)) << 4));
        *(f16x8*)&Ch[(size_t)(brow + row) * NQKV + bcol + (c16 << 3)] = vv;
    }
}

// ---------------------------------------------------------------- per-position attention
__global__ __launch_bounds__(256) void attn_kernel(const _Float16* __restrict__ QKVh,
                                                   float* __restrict__ out) {
    __shared__ _Float16 vlds[4][1024];
    __shared__ float attlds[4][16][16];

    const int w = threadIdx.x >> 6, l = threadIdx.x & 63;
    const size_t p = (size_t)blockIdx.x * 4 + w;
    const _Float16* base = QKVh + p * NQKV;
    const _Float16* qrow = base;
    const _Float16* krow = base + 1024;
    const _Float16* vrow = base + 2048;
    const int h = l & 15;
    const int g4 = (l >> 4) * 4;

    *(uint4*)&vlds[w][l * 16]     = *(const uint4*)&vrow[l * 16];
    *(uint4*)&vlds[w][l * 16 + 8] = *(const uint4*)&vrow[l * 16 + 8];

    const int fo = (l & 15) * HDIM + (l >> 4) * 8;
    f16x8 aK0 = *(const f16x8*)&krow[fo];
    f16x8 aK1 = *(const f16x8*)&krow[fo + 32];
    f16x8 bQ0 = *(const f16x8*)&qrow[fo];
    f16x8 bQ1 = *(const f16x8*)&qrow[fo + 32];

    f32x4 sT = {0.f, 0.f, 0.f, 0.f};
    sT = __builtin_amdgcn_mfma_f32_16x16x32_f16(aK0, bQ0, sT, 0, 0, 0);
    sT = __builtin_amdgcn_mfma_f32_16x16x32_f16(aK1, bQ1, sT, 0, 0, 0);
    // lane holds s[h = l&15][g = g4 + i] = sT[i]

    float m = fmaxf(fmaxf(sT[0], sT[1]), fmaxf(sT[2], sT[3]));
    m = fmaxf(m, __shfl_xor(m, 16));
    m = fmaxf(m, __shfl_xor(m, 32));
    float e0 = __expf(sT[0] - m), e1 = __expf(sT[1] - m);
    float e2 = __expf(sT[2] - m), e3 = __expf(sT[3] - m);
    float s = e0 + e1 + e2 + e3;
    s += __shfl_xor(s, 16);
    s += __shfl_xor(s, 32);
    const float inv = 1.0f / s;

    float4 att = make_float4(e0 * inv, e1 * inv, e2 * inv, e3 * inv);
    *(float4*)&attlds[w][h][g4] = att;
    __syncthreads();

    const int dbase = (l >> 4) * 16;
    float acc[16];
#pragma unroll
    for (int c = 0; c < 16; ++c) acc[c] = 0.f;

#pragma unroll
    for (int g = 0; g < 16; ++g) {
        const float av = attlds[w][h][g];
        f16x8 v0 = *(const f16x8*)&vlds[w][g * HDIM + dbase];
        f16x8 v1 = *(const f16x8*)&vlds[w][g * HDIM + dbase + 8];
#pragma unroll
        for (int c = 0; c < 8; ++c) {
            acc[c]     += av * (float)v0[c];
            acc[c + 8] += av * (float)v1[c];
        }
    }

    float* op = out + p * DIM + h * HDIM + dbase;
#pragma unroll
    for (int c = 0; c < 16; c += 4)
        *(float4*)(op + c) = make_float4(acc[c], acc[c + 1], acc[c + 2], acc[c + 3]);
}

// ---------------------------------------------------------------- launch
extern "C" void kernel_launch(void* const* d_in, const int* in_sizes, int n_in,
                              void* d_out, int out_size, void* d_ws, size_t ws_size,
                              hipStream_t stream) {
    const float* x  = (const float*)d_in[0];
    const float* Wq = (const float*)d_in[1];
    const float* bq = (const float*)d_in[2];
    const float* Wk = (const float*)d_in[3];
    const float* bk = (const float*)d_in[4];
    const float* Wv = (const float*)d_in[5];
    const float* bv = (const float*)d_in[6];
    float* out = (float*)d_out;

    char* ws = (char*)d_ws;
    // workspace: Xh 134217728 | Wth 6291456 | bias 12288 | Ch 402653184  (~518 MiB)
    _Float16* Xh  = (_Float16*)ws;
    _Float16* Wth = (_Float16*)(ws + 134217728);
    float*    bias = (float*)(ws + 134217728 + 6291456);
    _Float16* Ch  = (_Float16*)(ws + 134217728 + 6291456 + 12288);

    // allow 128 KiB dynamic LDS (gfx950 has 160 KiB/CU)
    (void)hipFuncSetAttribute((const void*)qkv_gemm_kernel,
                              hipFuncAttributeMaxDynamicSharedMemorySize, 131072);

    hipLaunchKernelGGL(cvt_x_kernel, dim3(2048), dim3(256), 0, stream,
                       x, Xh, (M_TOTAL * DIM) / 4);
    hipLaunchKernelGGL(cvt_w_kernel, dim3(32, 32, 3), dim3(32, 32), 0, stream,
                       Wq, Wk, Wv, Wth);
    hipLaunchKernelGGL(bias_kernel, dim3(12), dim3(256), 0, stream,
                       bq, bk, bv, bias);
    hipLaunchKernelGGL(qkv_gemm_kernel, dim3((M_TOTAL / 256) * (NQKV / 256)), dim3(512), 131072, stream,
                       Xh, Wth, bias, Ch);
    hipLaunchKernelGGL(attn_kernel, dim3(M_TOTAL / 4), dim3(256), 0, stream,
                       Ch, out);
}